// Round 16
// baseline (94.982 us; speedup 1.0000x reference)
//
#include <hip/hip_runtime.h>
#include <hip/hip_bf16.h>

#define SDIM 192
#define S2 (SDIM*SDIM)        // 36864
#define NCH 5
#define RAD 4                 // window 9

// ---- fused tiling: 8(h) x 64(w) tile, d-chunk 12 (+8 halo slices) ----
#define TW 64
#define TH 8
#define NWT (SDIM/TW)         // 3
#define NHT (SDIM/TH)         // 24
#define DCH 12
#define NDC (SDIM/DCH)        // 16
#define NSTEP (DCH + 2*RAD)   // 20
#define FGRID (NWT*NHT*NDC)   // 1152
#define NPART FGRID

#define SROW 16               // staged rows (8 + 2*4)
#define SQN 20                // staged quads per row (w0-8 .. w0+71)
#define SQS(Q) ((Q) + ((Q) >> 3))
#define IJW 88                // 4*SQS(19)=84, +4 slack
#define WFP 33                // 32 wf pairs + 1 pad

typedef float v2f __attribute__((ext_vector_type(2)));

__device__ __forceinline__ unsigned packbf(float lo, float hi) {
    __hip_bfloat162 h2 = __float22bfloat162_rn(make_float2(lo, hi));
    unsigned u; __builtin_memcpy(&u, &h2, 4); return u;
}
__device__ __forceinline__ float ulo(unsigned u) { return __uint_as_float(u << 16); }
__device__ __forceinline__ float uhi(unsigned u) { return __uint_as_float(u & 0xffff0000u); }

// ---------------- fused: W+H box filter per slice, D via packed-bf16 register ring, cc ----------------
__global__ __launch_bounds__(256) void fused_ncc(const float* __restrict__ pred,
                                                 const float* __restrict__ tgt,
                                                 float* __restrict__ partials) {
    const int b = blockIdx.x;             // (dc*NHT + ht)*NWT + wt
    const int wt = b % NWT;
    const int ht = (b / NWT) % NHT;
    const int dc = b / (NWT * NHT);
    const int w0 = wt * TW, h0 = ht * TH, d0 = dc * DCH;
    const int t = threadIdx.x;

    __shared__ unsigned IJ[SROW][IJW];          // packed {i,j} bf16, skewed quads — 5.6 KB
    __shared__ unsigned wfU[NCH][SROW][WFP];    // W-filtered, bf16x2 over w — 10.6 KB
    __shared__ float red[256];

    const float4* tg4 = (const float4*)tgt;
    const float4* pr4 = (const float4*)pred;

    const int wrow = t >> 4, wqu = t & 15;      // W-phase unit: row, quad-unit (4 cols)
    const int hr = t >> 5, wp = t & 31;         // H-phase unit: tile row, w-pair

    unsigned ring[NCH][9];                      // packed bf16x2 WH history (static idx)
    v2f z[NCH];
#pragma unroll
    for (int c = 0; c < NCH; ++c) {
        z[c] = (v2f)(0.f);
#pragma unroll
        for (int k = 0; k < 9; ++k) ring[c][k] = 0u;
    }

    v2f acc = (v2f)(0.f);
    const float inv = 1.0f / 729.0f;
    const float eps = 1.1920929e-07f;           // np.finfo(float32).eps
    const int gq0 = w0 / 4 - 2;                 // global quad of stage col 0

    for (int g = 0; g < 3; ++g) {               // 3 x 9-unrolled -> ring slot == k9
#pragma unroll
        for (int k9 = 0; k9 < 9; ++k9) {
            const int k = g * 9 + k9;
            if (k < NSTEP) {                    // block-uniform
                const int sa = d0 - RAD + k;
                const bool sval = (sa >= 0) && (sa < SDIM);   // block-uniform
                if (sval) {
                    const size_t sb4 = ((size_t)sa * S2) >> 2;
                    // stage: 16 rows x 20 quads, zero-masked outside volume
#pragma unroll
                    for (int it = 0; it < 2; ++it) {
                        const int u = t + 256 * it;
                        if (u < SROW * SQN) {
                            const int r = u / SQN, sq = u % SQN;
                            const int hh = h0 - RAD + r;
                            const int gq = gq0 + sq;
                            float4 vi = make_float4(0.f,0.f,0.f,0.f), vj = vi;
                            if (hh >= 0 && hh < SDIM && gq >= 0 && gq < 48) {
                                const size_t gi = sb4 + (size_t)hh * (SDIM/4) + gq;
                                vi = tg4[gi]; vj = pr4[gi];
                            }
                            uint4 w;
                            w.x = packbf(vi.x, vj.x); w.y = packbf(vi.y, vj.y);
                            w.z = packbf(vi.z, vj.z); w.w = packbf(vi.w, vj.w);
                            *(uint4*)&IJ[r][4 * SQS(sq)] = w;
                        }
                    }
                }
                __syncthreads();
                if (sval) {
                    // W: unit -> tile cols 4wqu..4wqu+3, reads stage quads wqu+1..wqu+3
                    const uint4 a  = *(const uint4*)&IJ[wrow][4 * SQS(wqu + 1)];
                    const uint4 bq = *(const uint4*)&IJ[wrow][4 * SQS(wqu + 2)];
                    const uint4 cq = *(const uint4*)&IJ[wrow][4 * SQS(wqu + 3)];
                    unsigned raw[12] = {a.x, a.y, a.z, a.w, bq.x, bq.y, bq.z, bq.w,
                                        cq.x, cq.y, cq.z, cq.w};
                    float fi[12], fj[12];
#pragma unroll
                    for (int kk = 0; kk < 12; ++kk) { fi[kk] = ulo(raw[kk]); fj[kk] = uhi(raw[kk]); }
#define W4(CH, EXPR) { \
                    float pv[12]; \
                    _Pragma("unroll") for (int kk = 0; kk < 12; ++kk) pv[kk] = (EXPR); \
                    float s0 = 0.f; \
                    _Pragma("unroll") for (int kk = 0; kk < 9; ++kk) s0 += pv[kk]; \
                    const float s1 = s0 - pv[0] + pv[9]; \
                    const float s2 = s1 - pv[1] + pv[10]; \
                    const float s3 = s2 - pv[2] + pv[11]; \
                    uint2 o; o.x = packbf(s0, s1); o.y = packbf(s2, s3); \
                    *(uint2*)&wfU[CH][wrow][2 * wqu] = o; }
                    W4(0, fi[kk])
                    W4(1, fj[kk])
                    W4(2, fi[kk] * fi[kk])
                    W4(3, fj[kk] * fj[kk])
                    W4(4, fi[kk] * fj[kk])
#undef W4
                }
                __syncthreads();
                // H (9-tap over rows) + ring/z update; WH=0 for invalid slices
#pragma unroll
                for (int c = 0; c < NCH; ++c) {
                    v2f wv = (v2f)(0.f);
                    if (sval) {
#pragma unroll
                        for (int dh = 0; dh < 9; ++dh) {
                            const unsigned u = wfU[c][hr + dh][wp];
                            wv += (v2f){ulo(u), uhi(u)};
                        }
                    }
                    const unsigned pu = sval ? packbf(wv.x, wv.y) : 0u;  // bf16 roundtrip
                    const unsigned old = ring[c][k9];
                    ring[c][k9] = pu;
                    z[c] += (v2f){ulo(pu), uhi(pu)} - (v2f){ulo(old), uhi(old)};
                }
                if (k >= 2 * RAD) {             // emit output d = sa - 4
                    const v2f mu1 = z[0] * inv, mu2 = z[1] * inv;
                    const v2f sg1 = z[2] * inv - mu1 * mu1;
                    const v2f sg2 = z[3] * inv - mu2 * mu2;
                    const v2f s12 = z[4] * inv - mu1 * mu2;
                    const v2f den = sg1 * sg2 + eps;
                    v2f rc;
                    rc.x = __builtin_amdgcn_rcpf(den.x);
                    rc.y = __builtin_amdgcn_rcpf(den.y);
                    acc += s12 * s12 * rc;
                }
            }
        }
    }

    red[t] = acc.x + acc.y;
    __syncthreads();
#pragma unroll
    for (int o = 128; o > 0; o >>= 1) {
        if (t < o) red[t] += red[t + o];
        __syncthreads();
    }
    if (t == 0) partials[b] = red[0];
}

// ---------------- K4: final deterministic reduction ----------------
__global__ __launch_bounds__(256) void k4_finalize(const float* __restrict__ partials,
                                                   float* __restrict__ out) {
    __shared__ float sm[256];
    float s = 0.f;
    for (int i = threadIdx.x; i < NPART; i += 256) s += partials[i];
    sm[threadIdx.x] = s;
    __syncthreads();
#pragma unroll
    for (int o = 128; o > 0; o >>= 1) {
        if (threadIdx.x < o) sm[threadIdx.x] += sm[threadIdx.x + o];
        __syncthreads();
    }
    if (threadIdx.x == 0) out[0] = 1.0f - sm[0] / (float)((size_t)SDIM * S2);
}

extern "C" void kernel_launch(void* const* d_in, const int* in_sizes, int n_in,
                              void* d_out, int out_size, void* d_ws, size_t ws_size,
                              hipStream_t stream) {
    const float* pred = (const float*)d_in[0];
    const float* tgt  = (const float*)d_in[1];
    float* out = (float*)d_out;

    float* partials = (float*)d_ws;

    fused_ncc<<<FGRID, 256, 0, stream>>>(pred, tgt, partials);
    k4_finalize<<<1, 256, 0, stream>>>(partials, out);
}

// Round 18
// 80.048 us; speedup vs baseline: 1.1866x; 1.1866x over previous
//
#include <hip/hip_runtime.h>
#include <hip/hip_bf16.h>

#define SDIM 192
#define S2 (SDIM*SDIM)        // 36864
#define S3 ((size_t)SDIM*S2)  // 7077888
#define NCH 5
#define RAD 4                 // window 9

// ---- KA: one d-slice, 8 output rows, full 192-w strip per block ----
#define STRH 8
#define RROW 16               // staged rows (8 + 2*4 halo)
// IJ raw storage: 50 quads (200 cols) skewed by SQ(Q)=Q+(Q>>3) -> 56 quads = 224 uints
#define RQU 224
#define WSTR 96               // uint (bf16x2) stride per wf row
#define NSTRIP (SDIM/STRH)    // 24
#define SQQ(Q) ((Q) + ((Q) >> 3))

// ---- KB: D-axis add/sub sliding window, uint2 (4 bf16) per thread, 1-wave blocks ----
#define KB_THR 64
#define KB_KBC 4                            // w-positions per thread (one uint2 = 4 bf16)
#define KB_POSB (S2/(KB_THR*KB_KBC))        // 144
#define KB_DCH 8
#define KB_NDC (SDIM/KB_DCH)                // 24
#define KB_GRID (KB_POSB*KB_NDC)            // 3456
#define NPART KB_GRID

typedef float v2f __attribute__((ext_vector_type(2)));
typedef unsigned v2u __attribute__((ext_vector_type(2)));

__device__ __forceinline__ unsigned packbf(float lo, float hi) {
    // scalar-cast pair -> compiler emits v_cvt_pk_bf16_f32
    __hip_bfloat162 h2 = __float22bfloat162_rn(make_float2(lo, hi));
    unsigned u; __builtin_memcpy(&u, &h2, 4); return u;
}
__device__ __forceinline__ float ulo(unsigned u) { return __uint_as_float(u << 16); }
__device__ __forceinline__ float uhi(unsigned u) { return __uint_as_float(u & 0xffff0000u); }

// ---------------- KA: W + H 9-tap (zero-padded) of the 5 product channels ----------------
__global__ __launch_bounds__(256) void ka_wh(const float* __restrict__ pred,
                                             const float* __restrict__ tgt,
                                             unsigned* __restrict__ BU) {
    const int b = blockIdx.x;              // d*NSTRIP + strip
    const int strip = b % NSTRIP;
    const int d = b / NSTRIP;
    const int h0 = strip * STRH;
    const size_t dbase = (size_t)d * S2;
    const int t = threadIdx.x;

    __shared__ unsigned IJ[RROW][RQU];          // packed {i(lo), j(hi)} bf16, skewed quads — 14.3 KB
    __shared__ unsigned wfU[NCH][RROW][WSTR];   // bf16x2 over w — 30.7 KB

    // zero pad quads: Q=0 (cols 0..3) at uint 0..3, Q=49 at uint 220..223
    if (t < RROW * 8) {
        const int r = t >> 3, p = t & 7;
        const int col = (p < 4) ? p : (216 + p);   // 0..3 / 220..223
        IJ[r][col] = 0u;
    }
    // stage interior rows: float4 global loads -> packed bf16{i,j} uint4 to skewed quad q+1
    const float4* tg4 = (const float4*)tgt;
    const float4* pr4 = (const float4*)pred;
#pragma unroll
    for (int it = 0; it < 3; ++it) {
        const int u = t + 256 * it;            // 0..767 == RROW*48-1, exact cover
        const int r = u / 48, q = u % 48;
        const int hh = h0 - RAD + r;
        float4 vi = make_float4(0.f, 0.f, 0.f, 0.f), vj = vi;
        if (hh >= 0 && hh < SDIM) {
            const size_t gi = (dbase + (size_t)hh * SDIM) / 4 + q;
            vi = tg4[gi]; vj = pr4[gi];
        }
        uint4 w;
        w.x = packbf(vi.x, vj.x); w.y = packbf(vi.y, vj.y);
        w.z = packbf(vi.z, vj.z); w.w = packbf(vi.w, vj.w);
        *(uint4*)&IJ[r][4 * SQQ(q + 1)] = w;
    }
    __syncthreads();

    // W phase: unit owns a ROW-PAIR x 4 output cols; packed-f32 math across the pair.
    // 8 row-pairs x 48 col-units = 384 units.
#pragma unroll
    for (int it = 0; it < 2; ++it) {
        const int u = t + 256 * it;
        if (u < (RROW / 2) * 48) {
            const int rp = u / 48, cu = u % 48;
            const int row0 = 2 * rp, row1 = row0 + 1;
            const uint4 a0 = *(const uint4*)&IJ[row0][4 * SQQ(cu)];
            const uint4 b0 = *(const uint4*)&IJ[row0][4 * SQQ(cu + 1)];
            const uint4 c0 = *(const uint4*)&IJ[row0][4 * SQQ(cu + 2)];
            const uint4 a1 = *(const uint4*)&IJ[row1][4 * SQQ(cu)];
            const uint4 b1 = *(const uint4*)&IJ[row1][4 * SQQ(cu + 1)];
            const uint4 c1 = *(const uint4*)&IJ[row1][4 * SQQ(cu + 2)];
            unsigned r0[12] = {a0.x, a0.y, a0.z, a0.w, b0.x, b0.y, b0.z, b0.w,
                               c0.x, c0.y, c0.z, c0.w};
            unsigned r1[12] = {a1.x, a1.y, a1.z, a1.w, b1.x, b1.y, b1.z, b1.w,
                               c1.x, c1.y, c1.z, c1.w};
            v2f fi[12], fj[12];
#pragma unroll
            for (int k = 0; k < 12; ++k) {
                fi[k] = (v2f){ulo(r0[k]), ulo(r1[k])};
                fj[k] = (v2f){uhi(r0[k]), uhi(r1[k])};
            }

#define W4P(CH, EXPR) { \
            v2f pv[12]; \
            _Pragma("unroll") for (int k = 0; k < 12; ++k) pv[k] = (EXPR); \
            v2f s0 = pv[0]; \
            _Pragma("unroll") for (int k = 1; k < 9; ++k) s0 += pv[k]; \
            const v2f s1 = s0 - pv[0] + pv[9]; \
            const v2f s2 = s1 - pv[1] + pv[10]; \
            const v2f s3 = s2 - pv[2] + pv[11]; \
            uint2 o0; o0.x = packbf(s0.x, s1.x); o0.y = packbf(s2.x, s3.x); \
            *(uint2*)&wfU[CH][row0][2 * cu] = o0; \
            uint2 o1; o1.x = packbf(s0.y, s1.y); o1.y = packbf(s2.y, s3.y); \
            *(uint2*)&wfU[CH][row1][2 * cu] = o1; }

            W4P(0, fi[k])
            W4P(1, fj[k])
            W4P(2, fi[k] * fi[k])
            W4P(3, fj[k] * fj[k])
            W4P(4, fi[k] * fj[k])
#undef W4P
        }
    }
    __syncthreads();

    // H phase: unit owns (channel, wp-PAIR): 240 units, single pass.
    // 16 ds_read_b64 + packed lo/hi sliding 9-sum + 8 nontemporal b64 stores.
    if (t < NCH * 48) {
        const int c = t / 48, wpp = t % 48;
        v2f va[RROW], vb[RROW];
#pragma unroll
        for (int r = 0; r < RROW; ++r) {
            const uint2 v = *(const uint2*)&wfU[c][r][2 * wpp];
            va[r] = (v2f){ulo(v.x), uhi(v.x)};
            vb[r] = (v2f){ulo(v.y), uhi(v.y)};
        }
        v2f sa = va[0], sb = vb[0];
#pragma unroll
        for (int r = 1; r < 9; ++r) { sa += va[r]; sb += vb[r]; }
        unsigned* dst = BU + (size_t)c * (S3 / 2) + (dbase + (size_t)h0 * SDIM) / 2 + 2 * wpp;
        v2u o;
        o.x = packbf(sa.x, sa.y); o.y = packbf(sb.x, sb.y);
        __builtin_nontemporal_store(o, (v2u*)dst);
#pragma unroll
        for (int hr = 1; hr < STRH; ++hr) {
            sa += va[hr + 8] - va[hr - 1];
            sb += vb[hr + 8] - vb[hr - 1];
            o.x = packbf(sa.x, sa.y); o.y = packbf(sb.x, sb.y);
            __builtin_nontemporal_store(o, (v2u*)(dst + hr * (SDIM / 2)));
        }
    }
}

// ---------------- KB: D-axis add/sub sliding window, uint2 loads, 1-wave blocks ----------------
#define SLICE2(s, OP) { const size_t sb = ((size_t)(s) * S2 + pos0) >> 2; \
    _Pragma("unroll") for (int c = 0; c < NCH; ++c) { \
        const uint2 v = B2[(size_t)c * (S3 >> 2) + sb]; \
        z[c][0] OP ulo(v.x); z[c][1] OP uhi(v.x); \
        z[c][2] OP ulo(v.y); z[c][3] OP uhi(v.y); } }

__global__ __launch_bounds__(KB_THR) void kb_d_cc(const unsigned* __restrict__ BU,
                                                  float* __restrict__ partials) {
    const int bid = blockIdx.x;
    const int dc = bid / KB_POSB;
    const int pb = bid % KB_POSB;
    const int d0 = dc * KB_DCH;
    const int pos0 = pb * (KB_THR * KB_KBC) + threadIdx.x * KB_KBC;
    const uint2* B2 = (const uint2*)BU;

    float z[NCH][KB_KBC];
#pragma unroll
    for (int c = 0; c < NCH; ++c)
#pragma unroll
        for (int i = 0; i < KB_KBC; ++i) z[c][i] = 0.f;

    // warm up: window for output d0 (slices d0-4..d0+4, zero-padded)
#pragma unroll
    for (int dd = -RAD; dd <= RAD; ++dd) {
        const int s = d0 + dd;
        if (s >= 0 && s < SDIM) SLICE2(s, +=)
    }

    const float inv = 1.0f / 729.0f;
    const float eps = 1.1920929e-07f;      // np.finfo(float32).eps
    float acc = 0.f;

#pragma unroll
    for (int k = 0; k < KB_DCH; ++k) {
        const int d = d0 + k;
#pragma unroll
        for (int i = 0; i < KB_KBC; ++i) {
            const float mu1 = z[0][i] * inv;
            const float mu2 = z[1][i] * inv;
            const float sg1 = z[2][i] * inv - mu1 * mu1;
            const float sg2 = z[3][i] * inv - mu2 * mu2;
            const float s12 = z[4][i] * inv - mu1 * mu2;
            acc += (s12 * s12) * __builtin_amdgcn_rcpf(sg1 * sg2 + eps);
        }
        const int da = d + RAD + 1;
        const int ds = d - RAD;
        if (da < SDIM) SLICE2(da, +=)
        if (ds >= 0)   SLICE2(ds, -=)
    }

    // single-wave deterministic shuffle reduction
#pragma unroll
    for (int off = 32; off > 0; off >>= 1)
        acc += __shfl_down(acc, off, 64);
    if (threadIdx.x == 0) partials[bid] = acc;
}

// ---------------- K4: final deterministic reduction ----------------
__global__ __launch_bounds__(256) void k4_finalize(const float* __restrict__ partials,
                                                   float* __restrict__ out) {
    __shared__ float sm[256];
    float s = 0.f;
    for (int i = threadIdx.x; i < NPART; i += 256) s += partials[i];
    sm[threadIdx.x] = s;
    __syncthreads();
#pragma unroll
    for (int o = 128; o > 0; o >>= 1) {
        if (threadIdx.x < o) sm[threadIdx.x] += sm[threadIdx.x + o];
        __syncthreads();
    }
    if (threadIdx.x == 0) out[0] = 1.0f - sm[0] / (float)((size_t)SDIM * S2);
}

extern "C" void kernel_launch(void* const* d_in, const int* in_sizes, int n_in,
                              void* d_out, int out_size, void* d_ws, size_t ws_size,
                              hipStream_t stream) {
    const float* pred = (const float*)d_in[0];
    const float* tgt  = (const float*)d_in[1];
    float* out = (float*)d_out;

    const size_t b_bytes = (size_t)NCH * S3 * sizeof(__hip_bfloat16);   // ~70.8 MB
    const size_t b_pad = (b_bytes + 255) & ~(size_t)255;

    unsigned* BU = (unsigned*)d_ws;
    float* partials = (float*)((char*)d_ws + b_pad);

    ka_wh<<<SDIM * NSTRIP, 256, 0, stream>>>(pred, tgt, BU);
    kb_d_cc<<<KB_GRID, KB_THR, 0, stream>>>(BU, partials);
    k4_finalize<<<1, 256, 0, stream>>>(partials, out);
}

// Round 19
// 73.198 us; speedup vs baseline: 1.2976x; 1.0936x over previous
//
#include <hip/hip_runtime.h>
#include <hip/hip_bf16.h>

#define SDIM 192
#define S2 (SDIM*SDIM)        // 36864
#define S3 ((size_t)SDIM*S2)  // 7077888
#define NCH 5
#define RAD 4                 // window 9

// ---- KA: one d-slice, 8 output rows, full 192-w strip per block ----
#define STRH 8
#define RROW 16               // staged rows (8 + 2*4 halo)
// IJ raw storage: 50 quads (200 cols) skewed by SQ(Q)=Q+(Q>>3) -> 56 quads = 224 uints
#define RQU 224
#define WSTR 96               // uint (bf16x2) stride per wf row
#define NSTRIP (SDIM/STRH)    // 24
#define SQQ(Q) ((Q) + ((Q) >> 3))

// ---- KB: D-axis add/sub sliding window, uint2 (4 bf16) per thread, 1-wave blocks ----
#define KB_THR 64
#define KB_KBC 4                            // w-positions per thread (one uint2 = 4 bf16)
#define KB_POSB (S2/(KB_THR*KB_KBC))        // 144
#define KB_DCH 8
#define KB_NDC (SDIM/KB_DCH)                // 24
#define KB_GRID (KB_POSB*KB_NDC)            // 3456
#define NPART KB_GRID

typedef float v2f __attribute__((ext_vector_type(2)));

__device__ __forceinline__ unsigned packbf(float lo, float hi) {
    // scalar-cast pair -> compiler emits v_cvt_pk_bf16_f32
    __hip_bfloat162 h2 = __float22bfloat162_rn(make_float2(lo, hi));
    unsigned u; __builtin_memcpy(&u, &h2, 4); return u;
}
__device__ __forceinline__ float ulo(unsigned u) { return __uint_as_float(u << 16); }
__device__ __forceinline__ float uhi(unsigned u) { return __uint_as_float(u & 0xffff0000u); }

// ---------------- KA: W + H 9-tap (zero-padded) of the 5 product channels ----------------
__global__ __launch_bounds__(256) void ka_wh(const float* __restrict__ pred,
                                             const float* __restrict__ tgt,
                                             unsigned* __restrict__ BU) {
    const int b = blockIdx.x;              // d*NSTRIP + strip
    const int strip = b % NSTRIP;
    const int d = b / NSTRIP;
    const int h0 = strip * STRH;
    const size_t dbase = (size_t)d * S2;
    const int t = threadIdx.x;

    __shared__ unsigned IJ[RROW][RQU];          // packed {i(lo), j(hi)} bf16, skewed quads — 14.3 KB
    __shared__ unsigned wfU[NCH][RROW][WSTR];   // bf16x2 over w — 30.7 KB

    // zero pad quads: Q=0 (cols 0..3) at uint 0..3, Q=49 at uint 220..223
    if (t < RROW * 8) {
        const int r = t >> 3, p = t & 7;
        const int col = (p < 4) ? p : (216 + p);   // 0..3 / 220..223
        IJ[r][col] = 0u;
    }
    // stage interior rows: float4 global loads -> packed bf16{i,j} uint4 to skewed quad q+1
    const float4* tg4 = (const float4*)tgt;
    const float4* pr4 = (const float4*)pred;
#pragma unroll
    for (int it = 0; it < 3; ++it) {
        const int u = t + 256 * it;            // 0..767 == RROW*48-1, exact cover
        const int r = u / 48, q = u % 48;
        const int hh = h0 - RAD + r;
        float4 vi = make_float4(0.f, 0.f, 0.f, 0.f), vj = vi;
        if (hh >= 0 && hh < SDIM) {
            const size_t gi = (dbase + (size_t)hh * SDIM) / 4 + q;
            vi = tg4[gi]; vj = pr4[gi];
        }
        uint4 w;
        w.x = packbf(vi.x, vj.x); w.y = packbf(vi.y, vj.y);
        w.z = packbf(vi.z, vj.z); w.w = packbf(vi.w, vj.w);
        *(uint4*)&IJ[r][4 * SQQ(q + 1)] = w;
    }
    __syncthreads();

    // W phase: unit owns a ROW-PAIR x 4 output cols; packed-f32 math across the pair.
    // 8 row-pairs x 48 col-units = 384 units.
#pragma unroll
    for (int it = 0; it < 2; ++it) {
        const int u = t + 256 * it;
        if (u < (RROW / 2) * 48) {
            const int rp = u / 48, cu = u % 48;
            const int row0 = 2 * rp, row1 = row0 + 1;
            const uint4 a0 = *(const uint4*)&IJ[row0][4 * SQQ(cu)];
            const uint4 b0 = *(const uint4*)&IJ[row0][4 * SQQ(cu + 1)];
            const uint4 c0 = *(const uint4*)&IJ[row0][4 * SQQ(cu + 2)];
            const uint4 a1 = *(const uint4*)&IJ[row1][4 * SQQ(cu)];
            const uint4 b1 = *(const uint4*)&IJ[row1][4 * SQQ(cu + 1)];
            const uint4 c1 = *(const uint4*)&IJ[row1][4 * SQQ(cu + 2)];
            unsigned r0[12] = {a0.x, a0.y, a0.z, a0.w, b0.x, b0.y, b0.z, b0.w,
                               c0.x, c0.y, c0.z, c0.w};
            unsigned r1[12] = {a1.x, a1.y, a1.z, a1.w, b1.x, b1.y, b1.z, b1.w,
                               c1.x, c1.y, c1.z, c1.w};
            v2f fi[12], fj[12];
#pragma unroll
            for (int k = 0; k < 12; ++k) {
                fi[k] = (v2f){ulo(r0[k]), ulo(r1[k])};
                fj[k] = (v2f){uhi(r0[k]), uhi(r1[k])};
            }

#define W4P(CH, EXPR) { \
            v2f pv[12]; \
            _Pragma("unroll") for (int k = 0; k < 12; ++k) pv[k] = (EXPR); \
            v2f s0 = pv[0]; \
            _Pragma("unroll") for (int k = 1; k < 9; ++k) s0 += pv[k]; \
            const v2f s1 = s0 - pv[0] + pv[9]; \
            const v2f s2 = s1 - pv[1] + pv[10]; \
            const v2f s3 = s2 - pv[2] + pv[11]; \
            uint2 o0; o0.x = packbf(s0.x, s1.x); o0.y = packbf(s2.x, s3.x); \
            *(uint2*)&wfU[CH][row0][2 * cu] = o0; \
            uint2 o1; o1.x = packbf(s0.y, s1.y); o1.y = packbf(s2.y, s3.y); \
            *(uint2*)&wfU[CH][row1][2 * cu] = o1; }

            W4P(0, fi[k])
            W4P(1, fj[k])
            W4P(2, fi[k] * fi[k])
            W4P(3, fj[k] * fj[k])
            W4P(4, fi[k] * fj[k])
#undef W4P
        }
    }
    __syncthreads();

    // H phase: unit owns (channel, wp-PAIR): 240 units, single pass.
    // 16 ds_read_b64 + packed lo/hi sliding 9-sum + 8 b64 stores.
    if (t < NCH * 48) {
        const int c = t / 48, wpp = t % 48;
        v2f va[RROW], vb[RROW];
#pragma unroll
        for (int r = 0; r < RROW; ++r) {
            const uint2 v = *(const uint2*)&wfU[c][r][2 * wpp];
            va[r] = (v2f){ulo(v.x), uhi(v.x)};
            vb[r] = (v2f){ulo(v.y), uhi(v.y)};
        }
        v2f sa = va[0], sb = vb[0];
#pragma unroll
        for (int r = 1; r < 9; ++r) { sa += va[r]; sb += vb[r]; }
        unsigned* dst = BU + (size_t)c * (S3 / 2) + (dbase + (size_t)h0 * SDIM) / 2 + 2 * wpp;
        uint2 o;
        o.x = packbf(sa.x, sa.y); o.y = packbf(sb.x, sb.y);
        *(uint2*)dst = o;
#pragma unroll
        for (int hr = 1; hr < STRH; ++hr) {
            sa += va[hr + 8] - va[hr - 1];
            sb += vb[hr + 8] - vb[hr - 1];
            o.x = packbf(sa.x, sa.y); o.y = packbf(sb.x, sb.y);
            *(uint2*)(dst + hr * (SDIM / 2)) = o;
        }
    }
}

// ---------------- KB: D-axis add/sub sliding window, uint2 loads, 1-wave blocks ----------------
#define SLICE2(s, OP) { const size_t sb = ((size_t)(s) * S2 + pos0) >> 2; \
    _Pragma("unroll") for (int c = 0; c < NCH; ++c) { \
        const uint2 v = B2[(size_t)c * (S3 >> 2) + sb]; \
        z[c][0] OP ulo(v.x); z[c][1] OP uhi(v.x); \
        z[c][2] OP ulo(v.y); z[c][3] OP uhi(v.y); } }

__global__ __launch_bounds__(KB_THR) void kb_d_cc(const unsigned* __restrict__ BU,
                                                  float* __restrict__ partials) {
    const int bid = blockIdx.x;
    const int dc = bid / KB_POSB;
    const int pb = bid % KB_POSB;
    const int d0 = dc * KB_DCH;
    const int pos0 = pb * (KB_THR * KB_KBC) + threadIdx.x * KB_KBC;
    const uint2* B2 = (const uint2*)BU;

    float z[NCH][KB_KBC];
#pragma unroll
    for (int c = 0; c < NCH; ++c)
#pragma unroll
        for (int i = 0; i < KB_KBC; ++i) z[c][i] = 0.f;

    // warm up: window for output d0 (slices d0-4..d0+4, zero-padded)
#pragma unroll
    for (int dd = -RAD; dd <= RAD; ++dd) {
        const int s = d0 + dd;
        if (s >= 0 && s < SDIM) SLICE2(s, +=)
    }

    const float inv = 1.0f / 729.0f;
    const float eps = 1.1920929e-07f;      // np.finfo(float32).eps
    float acc = 0.f;

#pragma unroll
    for (int k = 0; k < KB_DCH; ++k) {
        const int d = d0 + k;
#pragma unroll
        for (int i = 0; i < KB_KBC; ++i) {
            const float mu1 = z[0][i] * inv;
            const float mu2 = z[1][i] * inv;
            const float sg1 = z[2][i] * inv - mu1 * mu1;
            const float sg2 = z[3][i] * inv - mu2 * mu2;
            const float s12 = z[4][i] * inv - mu1 * mu2;
            acc += (s12 * s12) * __builtin_amdgcn_rcpf(sg1 * sg2 + eps);
        }
        const int da = d + RAD + 1;
        const int ds = d - RAD;
        if (da < SDIM) SLICE2(da, +=)
        if (ds >= 0)   SLICE2(ds, -=)
    }

    // single-wave deterministic shuffle reduction
#pragma unroll
    for (int off = 32; off > 0; off >>= 1)
        acc += __shfl_down(acc, off, 64);
    if (threadIdx.x == 0) partials[bid] = acc;
}

// ---------------- K4: final deterministic reduction ----------------
__global__ __launch_bounds__(256) void k4_finalize(const float* __restrict__ partials,
                                                   float* __restrict__ out) {
    __shared__ float sm[256];
    float s = 0.f;
    for (int i = threadIdx.x; i < NPART; i += 256) s += partials[i];
    sm[threadIdx.x] = s;
    __syncthreads();
#pragma unroll
    for (int o = 128; o > 0; o >>= 1) {
        if (threadIdx.x < o) sm[threadIdx.x] += sm[threadIdx.x + o];
        __syncthreads();
    }
    if (threadIdx.x == 0) out[0] = 1.0f - sm[0] / (float)((size_t)SDIM * S2);
}

extern "C" void kernel_launch(void* const* d_in, const int* in_sizes, int n_in,
                              void* d_out, int out_size, void* d_ws, size_t ws_size,
                              hipStream_t stream) {
    const float* pred = (const float*)d_in[0];
    const float* tgt  = (const float*)d_in[1];
    float* out = (float*)d_out;

    const size_t b_bytes = (size_t)NCH * S3 * sizeof(__hip_bfloat16);   // ~70.8 MB
    const size_t b_pad = (b_bytes + 255) & ~(size_t)255;

    unsigned* BU = (unsigned*)d_ws;
    float* partials = (float*)((char*)d_ws + b_pad);

    ka_wh<<<SDIM * NSTRIP, 256, 0, stream>>>(pred, tgt, BU);
    kb_d_cc<<<KB_GRID, KB_THR, 0, stream>>>(BU, partials);
    k4_finalize<<<1, 256, 0, stream>>>(partials, out);
}